// Round 9
// baseline (574.922 us; speedup 1.0000x reference)
//
#include <hip/hip_runtime.h>
#include <float.h>
#include <math.h>
#include <stdint.h>

#define M_ROWS 32768
#define K_CODES 8192
#define DDIM 256
#define BM 64
#define BN 128
#define NTILES (K_CODES / BN)   // 64
#define DELTA 0.009f
#define CAP 16

typedef __attribute__((ext_vector_type(8))) short short8;
typedef __attribute__((ext_vector_type(4))) float f32x4;

__device__ inline unsigned short f2bf(float f) {
    unsigned u = __float_as_uint(f);
    return (unsigned short)((u + 0x7fffu + ((u >> 16) & 1u)) >> 16);
}
__device__ inline unsigned fkey(float f) {
    unsigned u = __float_as_uint(f);
    return u ^ ((unsigned)((int)u >> 31) | 0x80000000u);
}
__device__ inline float fkey_inv(unsigned k) {
    unsigned u = (k & 0x80000000u) ? (k ^ 0x80000000u) : ~k;
    return __uint_as_float(u);
}

// ---------------- kernel 1: normalize E -> En (fp32) + En_b (bf16) ----------------
__global__ __launch_bounds__(256) void k_norm_E(const float* __restrict__ E,
                                                float* __restrict__ En,
                                                unsigned short* __restrict__ En_b) {
    int wid  = threadIdx.x >> 6;
    int lane = threadIdx.x & 63;
    int row  = blockIdx.x * 4 + wid;
    const float* e = E + (size_t)row * DDIM;
    float v[4];
    float ssq = 0.f;
#pragma unroll
    for (int p = 0; p < 4; ++p) { v[p] = e[lane + 64 * p]; ssq += v[p] * v[p]; }
#pragma unroll
    for (int off = 32; off >= 1; off >>= 1) ssq += __shfl_xor(ssq, off);
    float inv = 1.f / fmaxf(sqrtf(ssq), 1e-8f);
    float* o = En + (size_t)row * DDIM;
    unsigned short* ob = En_b + (size_t)row * DDIM;
#pragma unroll
    for (int p = 0; p < 4; ++p) {
        float nv = v[p] * inv;
        o[lane + 64 * p]  = nv;
        ob[lane + 64 * p] = f2bf(nv);
    }
}

// ---------------- kernel 2: two-pass MFMA filter, B direct global->VGPR ----------
// 512 thr = 8 waves. Each wave owns 16 codes (wc=wid) of the BN=128 tile and
// ALL BM=64 rows (af[4][8] in registers). B-fragments are loaded straight from
// global into a register double buffer (bA/bB) -- no LDS in the hot loop.
// Pass A: register fmax -> exact row max. Pass B: recompute, emit >= max-DELTA.
__global__ __launch_bounds__(512, 2) void k_cand(
    const float* __restrict__ z,
    const unsigned short* __restrict__ En_b,
    unsigned char* __restrict__ cand_cnt,
    int* __restrict__ cand_k) {

    __shared__ unsigned rowmaxKey[BM];
    __shared__ int cnt[BM];
    __shared__ int list[BM][CAP];

    const int tid  = threadIdx.x;
    const int lane = tid & 63;
    const int wid  = tid >> 6;      // col-group 0..7
    const int lo   = lane & 15;
    const int hi   = lane >> 4;
    const int m0   = blockIdx.x * BM;

    if (tid < BM) { cnt[tid] = 0; rowmaxKey[tid] = 0u; }
    __syncthreads();

    // per-lane B base: code row = wid*16+lo, 16B sub-column hi within each 64B
    const char* bbase = (const char*)En_b + (size_t)(wid * 16 + lo) * 512 + hi * 16;

#define LOADT(buf, t)                                                           \
    {                                                                           \
        const char* bp_ = bbase + (size_t)(t) * (BN * 512);                     \
        _Pragma("unroll")                                                       \
        for (int ks_ = 0; ks_ < 8; ++ks_)                                       \
            buf[ks_] = *(const short8*)(bp_ + ks_ * 64);                        \
    }

    // issue first tile load early (covers af-setup latency)
    short8 bA[8], bB[8];
    LOADT(bA, 0);

    // ---- A fragments: load z fp32, normalize in-register, cvt bf16 ----
    // af[mi][ks]: row = mi*16 + lo (same rows for all 8 waves)
    short8 af[4][8];
#pragma unroll
    for (int mi = 0; mi < 4; ++mi) {
        const float* zr = z + (size_t)(m0 + mi * 16 + lo) * DDIM;
        float4 v[16];
        float ssq = 0.f;
#pragma unroll
        for (int ks = 0; ks < 8; ++ks) {
            int e0 = (ks * 4 + hi) * 8;
            v[2 * ks]     = *(const float4*)&zr[e0];
            v[2 * ks + 1] = *(const float4*)&zr[e0 + 4];
            float4 a = v[2 * ks], b = v[2 * ks + 1];
            ssq += a.x * a.x + a.y * a.y + a.z * a.z + a.w * a.w;
            ssq += b.x * b.x + b.y * b.y + b.z * b.z + b.w * b.w;
        }
        // 4 hi-lanes hold disjoint 64-element subsets of the row
        ssq += __shfl_xor(ssq, 16);
        ssq += __shfl_xor(ssq, 32);
        float inv = 1.f / fmaxf(sqrtf(ssq), 1e-8f);
#pragma unroll
        for (int ks = 0; ks < 8; ++ks) {
            float4 a = v[2 * ks], b = v[2 * ks + 1];
            short8 s8;
            s8[0] = (short)f2bf(a.x * inv); s8[1] = (short)f2bf(a.y * inv);
            s8[2] = (short)f2bf(a.z * inv); s8[3] = (short)f2bf(a.w * inv);
            s8[4] = (short)f2bf(b.x * inv); s8[5] = (short)f2bf(b.y * inv);
            s8[6] = (short)f2bf(b.z * inv); s8[7] = (short)f2bf(b.w * inv);
            af[mi][ks] = s8;
        }
    }

#define MFMA_TILE(buf, acc)                                                     \
    _Pragma("unroll")                                                           \
    for (int ks_ = 0; ks_ < 8; ++ks_) {                                         \
        _Pragma("unroll")                                                       \
        for (int mi_ = 0; mi_ < 4; ++mi_)                                       \
            acc[mi_] = __builtin_amdgcn_mfma_f32_16x16x32_bf16(                 \
                af[mi_][ks_], buf[ks_], acc[mi_], 0, 0, 0);                     \
    }

    // ================= PASS A: exact row max =================
    float pmax[16];
#pragma unroll
    for (int s = 0; s < 16; ++s) pmax[s] = -FLT_MAX;

#define COMPA(buf)                                                              \
    {                                                                           \
        f32x4 acc[4];                                                           \
        _Pragma("unroll") for (int mi_ = 0; mi_ < 4; ++mi_)                     \
            acc[mi_] = (f32x4){0.f, 0.f, 0.f, 0.f};                             \
        MFMA_TILE(buf, acc)                                                     \
        _Pragma("unroll") for (int mi_ = 0; mi_ < 4; ++mi_)                     \
            _Pragma("unroll") for (int r_ = 0; r_ < 4; ++r_)                    \
                pmax[mi_ * 4 + r_] = fmaxf(pmax[mi_ * 4 + r_], acc[mi_][r_]);   \
    }

    for (int t = 0; t < NTILES; t += 2) {
        LOADT(bB, t + 1);
        COMPA(bA);
        if (t + 2 < NTILES) LOADT(bA, t + 2);
        COMPA(bB);
    }

    // reduce row max across the 16 lo-lanes, publish via LDS atomicMax
#pragma unroll
    for (int s = 0; s < 16; ++s) {
        float w = pmax[s];
        w = fmaxf(w, __shfl_xor(w, 1));
        w = fmaxf(w, __shfl_xor(w, 2));
        w = fmaxf(w, __shfl_xor(w, 4));
        w = fmaxf(w, __shfl_xor(w, 8));
        if (lo == 0) {
            int row = (s >> 2) * 16 + hi * 4 + (s & 3);
            atomicMax(&rowmaxKey[row], fkey(w));
        }
    }
    __syncthreads();   // all waves' maxima published

    float thr[16];
#pragma unroll
    for (int s = 0; s < 16; ++s) {
        int row = (s >> 2) * 16 + hi * 4 + (s & 3);
        thr[s] = fkey_inv(rowmaxKey[row]) - DELTA;
    }

    // ================= PASS B: emit candidates =================
#define COMPB(buf, t)                                                           \
    {                                                                           \
        f32x4 acc[4];                                                           \
        _Pragma("unroll") for (int mi_ = 0; mi_ < 4; ++mi_)                     \
            acc[mi_] = (f32x4){0.f, 0.f, 0.f, 0.f};                             \
        MFMA_TILE(buf, acc)                                                     \
        const int kv_ = (t) * BN + wid * 16 + lo;                               \
        _Pragma("unroll") for (int mi_ = 0; mi_ < 4; ++mi_)                     \
            _Pragma("unroll") for (int r_ = 0; r_ < 4; ++r_) {                  \
                if (acc[mi_][r_] >= thr[mi_ * 4 + r_]) {                        \
                    int row_ = mi_ * 16 + hi * 4 + r_;                          \
                    int pos_ = atomicAdd(&cnt[row_], 1);                        \
                    if (pos_ < CAP) list[row_][pos_] = kv_;                     \
                }                                                               \
            }                                                                   \
    }

    LOADT(bA, 0);
    for (int t = 0; t < NTILES; t += 2) {
        LOADT(bB, t + 1);
        COMPB(bA, t);
        if (t + 2 < NTILES) LOADT(bA, t + 2);
        COMPB(bB, t + 1);
    }
    __syncthreads();   // lists complete

    if (tid < BM) {
        int c = cnt[tid];
        cand_cnt[m0 + tid] = (unsigned char)(c > CAP ? 255 : c);
        int n = c < CAP ? c : CAP;
        for (int j = 0; j < n; ++j) cand_k[(size_t)(m0 + tid) * CAP + j] = list[tid][j];
    }
#undef LOADT
#undef MFMA_TILE
#undef COMPA
#undef COMPB
}

// ---------------- kernel 3: rescore + gather / zq_st / per-row loss / idx ----------------
__global__ __launch_bounds__(256) void k_final(const float* __restrict__ z,
                                               const float* __restrict__ E,
                                               const float* __restrict__ En,
                                               const unsigned char* __restrict__ cand_cnt,
                                               const int* __restrict__ cand_k,
                                               float* __restrict__ out,
                                               float* __restrict__ rowloss) {
    __shared__ float zl[4][256];
    int wid  = threadIdx.x >> 6;
    int lane = threadIdx.x & 63;
    int m    = blockIdx.x * 4 + wid;

    const float* zr = z + (size_t)m * DDIM;
    const float4 zz = *(const float4*)&zr[lane * 4];

    int   c  = cand_cnt[m];
    float bv = -FLT_MAX;
    int   bk = 0x7fffffff;
    if (c != 255) {
        for (int j = 0; j < c; ++j) {
            int k = cand_k[(size_t)m * CAP + j];
            const float4 ee = *(const float4*)&En[(size_t)k * DDIM + lane * 4];
            float s = zz.x * ee.x + zz.y * ee.y + zz.z * ee.z + zz.w * ee.w;
#pragma unroll
            for (int off = 1; off < 64; off <<= 1) s += __shfl_xor(s, off);
            if (s > bv || (s == bv && k < bk)) { bv = s; bk = k; }
        }
    } else {
        // insurance fallback: wave-parallel full fp32 scan, z staged in LDS
        *(float4*)&zl[wid][lane * 4] = zz;
        asm volatile("s_waitcnt lgkmcnt(0)" ::: "memory");
        for (int kb = 0; kb < K_CODES; kb += 64) {
            int k = kb + lane;
            const float4* er = (const float4*)&En[(size_t)k * DDIM];
            float s0 = 0.f, s1 = 0.f, s2 = 0.f, s3 = 0.f;
#pragma unroll 8
            for (int d4 = 0; d4 < 64; ++d4) {
                float4 e  = er[d4];
                float4 zd = *(const float4*)&zl[wid][d4 * 4];
                s0 += zd.x * e.x; s1 += zd.y * e.y;
                s2 += zd.z * e.z; s3 += zd.w * e.w;
            }
            float s = (s0 + s1) + (s2 + s3);
            if (s > bv || (s == bv && k < bk)) { bv = s; bk = k; }
        }
#pragma unroll
        for (int off = 1; off < 64; off <<= 1) {
            float ov = __shfl_xor(bv, off);
            int   ok = __shfl_xor(bk, off);
            if (ov > bv || (ov == bv && ok < bk)) { bv = ov; bk = ok; }
        }
    }
    const int idx = bk;

    const float* er = E + (size_t)idx * DDIM;
    float zv[4], ev[4];
    float sz = 0.f, se = 0.f;
#pragma unroll
    for (int p = 0; p < 4; ++p) {
        zv[p] = zr[lane + 64 * p]; sz += zv[p] * zv[p];
        ev[p] = er[lane + 64 * p]; se += ev[p] * ev[p];
    }
#pragma unroll
    for (int off = 32; off >= 1; off >>= 1) {
        sz += __shfl_xor(sz, off);
        se += __shfl_xor(se, off);
    }
    float nz = fmaxf(sqrtf(sz), 1e-8f);
    float ne = fmaxf(sqrtf(se), 1e-8f);

    float rs = 0.f;
    float* zq = out + 1 + (size_t)m * DDIM;
#pragma unroll
    for (int p = 0; p < 4; ++p) {
        float zn = zv[p] / nz;
        float en = ev[p] / ne;
        float d  = en - zn;
        rs += d * d;
        zq[lane + 64 * p] = zv[p] + (ev[p] - zv[p]);
    }
#pragma unroll
    for (int off = 32; off >= 1; off >>= 1) rs += __shfl_xor(rs, off);

    if (lane == 0) {
        rowloss[m] = rs;
        out[1 + (size_t)M_ROWS * DDIM + m] = (float)idx;
    }
}

// ---------------- kernel 4: deterministic loss reduction ----------------
__global__ __launch_bounds__(256) void k_loss(const float* __restrict__ rowloss,
                                              float* __restrict__ out) {
    __shared__ double sm[256];
    double s = 0.0;
    for (int i = threadIdx.x; i < M_ROWS; i += 256) s += (double)rowloss[i];
    sm[threadIdx.x] = s;
    __syncthreads();
    for (int st = 128; st > 0; st >>= 1) {
        if (threadIdx.x < st) sm[threadIdx.x] += sm[threadIdx.x + st];
        __syncthreads();
    }
    if (threadIdx.x == 0) {
        float c = (float)(sm[0] / (double)((size_t)M_ROWS * DDIM));
        out[0] = c + 0.05f * c;
    }
}

extern "C" void kernel_launch(void* const* d_in, const int* in_sizes, int n_in,
                              void* d_out, int out_size, void* d_ws, size_t ws_size,
                              hipStream_t stream) {
    const float* z = (const float*)d_in[0];
    const float* E = (const float*)d_in[1];
    float* out = (float*)d_out;

    char* ws = (char*)d_ws;
    size_t off = 0;
    float*          En       = (float*)(ws + off);          off += (size_t)K_CODES * DDIM * 4;  // 8 MB
    unsigned short* En_b     = (unsigned short*)(ws + off); off += (size_t)K_CODES * DDIM * 2;  // 4 MB
    int*            cand_k   = (int*)(ws + off);            off += (size_t)M_ROWS * CAP * 4;    // 2 MB
    unsigned char*  cand_cnt = (unsigned char*)(ws + off);  off += (size_t)M_ROWS;              // 32 KB
    float*          rowloss  = (float*)(ws + off);

    k_norm_E<<<K_CODES / 4, 256, 0, stream>>>(E, En, En_b);
    k_cand<<<M_ROWS / BM, 512, 0, stream>>>(z, En_b, cand_cnt, cand_k);
    k_final<<<M_ROWS / 4, 256, 0, stream>>>(z, E, En, cand_cnt, cand_k, out, rowloss);
    k_loss<<<1, 256, 0, stream>>>(rowloss, out);
}